// Round 1
// baseline (1229.971 us; speedup 1.0000x reference)
//
#include <hip/hip_runtime.h>
#include <hip/hip_fp16.h>
#include <stdint.h>

namespace {
constexpr int B = 4, C = 384, Wd = 256, HW = 65536;
constexpr int NH = 8, HD = 48, SH = 4;
constexpr float SCALE = 0.14433756729740643f;   // 48^-0.5
constexpr int CH = C / 2;                        // 192 channels per score-partial

// ---------------- kernel 1: Qg[b,c] = mean over HW of X_f ----------------
__global__ __launch_bounds__(256) void k_mean(const float* __restrict__ Xf,
                                              float* __restrict__ Qg) {
  int bc = blockIdx.x;
  const float4* p = reinterpret_cast<const float4*>(Xf + (size_t)bc * HW);
  float s = 0.f;
  for (int it = threadIdx.x; it < HW / 4; it += 256) {
    float4 v = p[it];
    s += (v.x + v.y) + (v.z + v.w);
  }
  __shared__ float red[256];
  red[threadIdx.x] = s;
  __syncthreads();
  for (int off = 128; off > 0; off >>= 1) {
    if (threadIdx.x < off) red[threadIdx.x] += red[threadIdx.x + off];
    __syncthreads();
  }
  if (threadIdx.x == 0) Qg[bc] = red[0] * (1.0f / HW);
}

// ---------------- kernel 2: Q = Qg@Wq.T + bq ; Qk[b,h,c] = sum_d Q[b,h,d]*Wk[h*HD+d,c]
__global__ __launch_bounds__(256) void k_proj(const float* __restrict__ Qg,
                                              const float* __restrict__ Wq,
                                              const float* __restrict__ bq,
                                              const float* __restrict__ Wk,
                                              float* __restrict__ Qk) {
  __shared__ float Qs[B * C];
  int t = threadIdx.x;
  for (int idx = t; idx < B * C; idx += 256) {
    int b = idx / C, o = idx % C;
    const float* qg = Qg + b * C;
    const float* w = Wq + (size_t)o * C;
    float s = bq[o];
    for (int c = 0; c < C; c++) s += qg[c] * w[c];
    Qs[idx] = s;
  }
  __syncthreads();
  for (int idx = t; idx < B * NH * C; idx += 256) {
    int c = idx % C;
    int bh = idx / C;
    int h = bh % NH, b = bh / NH;
    float s = 0.f;
    for (int d = 0; d < HD; d++)
      s += Qs[b * C + h * HD + d] * Wk[(size_t)(h * HD + d) * C + c];
    Qk[idx] = s;   // layout [b][h][c]
  }
  // note: bk-term is constant per (b,h) across the 64 window slots -> softmax-invariant, dropped
}

// ---------------- kernel 3: partial scores over a half of the channels ----------------
// block = (b, rowgrp of 4 source rows, chalf); thread = (row r, 4 consecutive cols)
__global__ __launch_bounds__(256) void k_scores(const float* __restrict__ Xs,
                                                const float* __restrict__ Qk,
                                                float* __restrict__ Sp) {
  int x = blockIdx.x;          // 512 blocks
  int b = x >> 7;
  int rowgrp = (x >> 1) & 63;
  int chalf = x & 1;
  int c0 = chalf * CH;
  float* Spart = Sp + (size_t)chalf * ((size_t)B * NH * HW);

  __shared__ __align__(16) float qk[CH * 8];     // [cl][h], 6 KB
  for (int idx = threadIdx.x; idx < CH * 8; idx += 256) {
    int cl = idx >> 3, h = idx & 7;
    qk[idx] = Qk[((size_t)(b * NH + h)) * C + c0 + cl];
  }
  __syncthreads();

  int r = threadIdx.x >> 6;
  int j4 = (threadIdx.x & 63) * 4;
  int si = rowgrp * 4 + r;

  float acc[4][8];
#pragma unroll
  for (int p = 0; p < 4; p++)
#pragma unroll
    for (int h = 0; h < NH; h++) acc[p][h] = 0.f;

  const float* xp = Xs + ((size_t)(b * C + c0)) * HW + si * Wd + j4;
#pragma unroll 4
  for (int cl = 0; cl < CH; cl++) {
    float4 xv = *reinterpret_cast<const float4*>(xp + (size_t)cl * HW);
    float4 q0 = *reinterpret_cast<const float4*>(&qk[cl * 8]);
    float4 q1 = *reinterpret_cast<const float4*>(&qk[cl * 8 + 4]);
    float qv[8] = {q0.x, q0.y, q0.z, q0.w, q1.x, q1.y, q1.z, q1.w};
    float xa[4] = {xv.x, xv.y, xv.z, xv.w};
#pragma unroll
    for (int p = 0; p < 4; p++)
#pragma unroll
      for (int h = 0; h < NH; h++) acc[p][h] += xa[p] * qv[h];
  }

  // rolled coords: i=(si+4)&255, j=(sj+4)&255 ; shift=4 divides 4 so float4 store stays aligned
  int i = (si + SH) & 255;
  int js = (j4 + SH) & 255;
#pragma unroll
  for (int h = 0; h < NH; h++) {
    float4 o = make_float4(acc[0][h], acc[1][h], acc[2][h], acc[3][h]);
    *reinterpret_cast<float4*>(Spart + ((size_t)(b * NH + h)) * HW + i * Wd + js) = o;
  }
}

// ---------------- kernel 4: per-window softmax (wave64 = 64 slots), pack 8 fp16 weights/pixel
__global__ __launch_bounds__(256) void k_softmax(const float* __restrict__ Sp,
                                                 uint16_t* __restrict__ Wb) {
  const float* S0 = Sp;
  const float* S1 = Sp + (size_t)B * NH * HW;
  int wid = threadIdx.x >> 6, lane = threadIdx.x & 63;
  int gid = blockIdx.x * 4 + wid;          // 0..4095 = (b, window)
  int b = gid >> 10;
  int w = gid & 1023;
  int i = (w >> 5) * 8 + (lane >> 3);
  int j = (w & 31) * 8 + (lane & 7);

  union { __half h[8]; uint4 u; } pk;
#pragma unroll
  for (int h = 0; h < NH; h++) {
    size_t idx = ((size_t)(b * NH + h)) * HW + i * Wd + j;
    float s = (S0[idx] + S1[idx]) * SCALE;
    float m = s;
#pragma unroll
    for (int o = 32; o > 0; o >>= 1) m = fmaxf(m, __shfl_xor(m, o));
    float e = __expf(s - m);
    float sum = e;
#pragma unroll
    for (int o = 32; o > 0; o >>= 1) sum += __shfl_xor(sum, o);
    pk.h[h] = __float2half(e / sum);
  }
  uint4* dst = reinterpret_cast<uint4*>(Wb) + (size_t)b * HW + i * Wd + j;
  *dst = pk.u;
}

// ---------------- kernel 5: Y[b,h,c] = sum_pos w[b,h,pos] * X_s[b,c,src(pos)] ----------------
__global__ __launch_bounds__(256) void k_pool(const float* __restrict__ Xs,
                                              const uint16_t* __restrict__ Wb,
                                              float* __restrict__ Y) {
  int bc = blockIdx.x;                 // c-major within b -> same-b blocks co-resident (L2)
  int b = bc / C, c = bc % C;
  int sj = threadIdx.x;
  int jw = (sj + SH) & 255;
  const float* xp = Xs + (size_t)bc * HW + sj;
  const uint4* wp = reinterpret_cast<const uint4*>(Wb) + (size_t)b * HW + jw;

  float acc[8];
#pragma unroll
  for (int h = 0; h < 8; h++) acc[h] = 0.f;

#pragma unroll 2
  for (int si = 0; si < 256; si++) {
    float xv = xp[(size_t)si * Wd];
    int iw = (si + SH) & 255;
    uint4 wv = wp[(size_t)iw * Wd];
    const __half2* h2 = reinterpret_cast<const __half2*>(&wv);
#pragma unroll
    for (int k = 0; k < 4; k++) {
      float2 f = __half22float2(h2[k]);
      acc[2 * k] += xv * f.x;
      acc[2 * k + 1] += xv * f.y;
    }
  }

  __shared__ float red[256];
  for (int h = 0; h < 8; h++) {
    red[threadIdx.x] = acc[h];
    __syncthreads();
    for (int off = 128; off > 0; off >>= 1) {
      if (threadIdx.x < off) red[threadIdx.x] += red[threadIdx.x + off];
      __syncthreads();
    }
    if (threadIdx.x == 0) Y[((size_t)(b * NH + h)) * C + c] = red[0];
    __syncthreads();
  }
}

// ---------------- kernel 6: o_pre = Wv·Y/nW + bv ; final = Wo·o_pre + bo ----------------
__global__ __launch_bounds__(384) void k_head(const float* __restrict__ Y,
                                              const float* __restrict__ Wv,
                                              const float* __restrict__ bv,
                                              const float* __restrict__ Wo,
                                              const float* __restrict__ bo,
                                              float* __restrict__ Fin) {
  int b = blockIdx.x;
  int o = threadIdx.x;                 // 384 threads
  __shared__ float op[C];
  int h = o / HD;
  const float* y = Y + (size_t)(b * NH + h) * C;
  const float* w = Wv + (size_t)o * C;
  float s = 0.f;
  for (int c = 0; c < C; c++) s += w[c] * y[c];
  op[o] = s * (1.0f / 1024.0f) + bv[o];
  __syncthreads();
  const float* w2 = Wo + (size_t)o * C;
  float s2 = bo[o];
  for (int c = 0; c < C; c++) s2 += w2[c] * op[c];
  Fin[b * C + o] = s2;
}

// ---------------- kernel 7: broadcast (B,C) -> (B,C,H,W) ----------------
__global__ __launch_bounds__(256) void k_bcast(const float* __restrict__ Fin,
                                               float* __restrict__ Out) {
  int bc = blockIdx.x;
  float v = Fin[bc];
  float4 v4 = make_float4(v, v, v, v);
  float4* op = reinterpret_cast<float4*>(Out + (size_t)bc * HW);
  for (int it = threadIdx.x; it < HW / 4; it += 256) op[it] = v4;
}

}  // namespace

extern "C" void kernel_launch(void* const* d_in, const int* in_sizes, int n_in,
                              void* d_out, int out_size, void* d_ws, size_t ws_size,
                              hipStream_t stream) {
  const float* Xf = (const float*)d_in[0];
  const float* Xs = (const float*)d_in[1];
  const float* Wq = (const float*)d_in[2];
  const float* bq = (const float*)d_in[3];
  const float* Wk = (const float*)d_in[4];
  // d_in[5] = bk : softmax-invariant, unused
  const float* Wv = (const float*)d_in[6];
  const float* bv = (const float*)d_in[7];
  const float* Wo = (const float*)d_in[8];
  const float* bo = (const float*)d_in[9];
  float* Out = (float*)d_out;

  char* ws = (char*)d_ws;
  uint16_t* Wb = (uint16_t*)(ws);                      // 4 MB packed fp16 weights [b][pos][h]
  float* Sp = (float*)(ws + ((size_t)4 << 20));        // 2 x 8 MB score partials
  char* tail = ws + ((size_t)20 << 20);
  float* Qg = (float*)(tail);                          // 6 KB
  float* Qk = (float*)(tail + 6144);                   // 48 KB
  float* Y = (float*)(tail + 6144 + 49152);            // 48 KB
  float* Fin = (float*)(tail + 6144 + 49152 + 49152);  // 6 KB

  k_mean<<<B * C, 256, 0, stream>>>(Xf, Qg);
  k_proj<<<1, 256, 0, stream>>>(Qg, Wq, bq, Wk, Qk);
  k_scores<<<512, 256, 0, stream>>>(Xs, Qk, Sp);
  k_softmax<<<1024, 256, 0, stream>>>(Sp, Wb);
  k_pool<<<B * C, 256, 0, stream>>>(Xs, Wb, Y);
  k_head<<<B, 384, 0, stream>>>(Y, Wv, bv, Wo, bo, Fin);
  k_bcast<<<B * C, 256, 0, stream>>>(Fin, Out);
}